// Round 1
// baseline (269.198 us; speedup 1.0000x reference)
//
#include <hip/hip_runtime.h>
#include <math.h>

#define Bb   256
#define Lq   128
#define D1   768
#define Hh   1024
#define Kk   256
#define K2v  512

// ws layout (float offsets)
#define WS_H1    0                         // 512*1024
#define WS_Z     (512*1024)                // 512*256
#define WS_SCORE (WS_Z + 512*256)          // 512*256
#define WS_DIST  (WS_SCORE + 512*256)      // 65536
#define WS_YSY   (WS_DIST + 65536)         // 256
#define WS_SEQL  (WS_YSY + 256)            // 256 ints
#define WS_SCAL  (WS_SEQL + 256)           // [0]=kl_img [1]=kl_txt [2]=align [3]=bw2

__device__ __forceinline__ float wred(float v){
#pragma unroll
  for (int m = 32; m; m >>= 1) v += __shfl_xor(v, m, 64);
  return v;
}
__device__ __forceinline__ int wredi(int v){
#pragma unroll
  for (int m = 32; m; m >>= 1) v += __shfl_xor(v, m, 64);
  return v;
}
__device__ __forceinline__ float gelu_exact(float x){
  return 0.5f * x * (1.0f + erff(x * 0.70710678118654752f));
}
__device__ __forceinline__ void fma4(float4& a, float s, const float4 w){
  a.x = fmaf(s, w.x, a.x); a.y = fmaf(s, w.y, a.y);
  a.z = fmaf(s, w.z, a.z); a.w = fmaf(s, w.w, a.w);
}

// ---------------- K0: seq_last[b] = sum(mask[b,:]) - 1 ----------------
__global__ void k_seqlast(const int* __restrict__ mask, int* __restrict__ seql){
  int b = threadIdx.x;
  const int4* m4 = reinterpret_cast<const int4*>(mask + b * Lq);
  int s = 0;
#pragma unroll
  for (int i = 0; i < Lq / 4; i++){ int4 v = m4[i]; s += v.x + v.y + v.z + v.w; }
  seql[b] = s - 1;
}

// ---------------- K1: gathered-row GEMM1  h1 = x @ W1 + b1  (pre-LN) ----------------
// grid (4 coltiles, 32 rowgroups, 2 mods), 256 threads; 8 rows x 256 cols per block
__global__ __launch_bounds__(256) void k_enc_gemm1(
    const float* __restrict__ img, const float* __restrict__ txt,
    const float* __restrict__ W1i, const float* __restrict__ W1t,
    const float* __restrict__ b1i, const float* __restrict__ b1t,
    const int* __restrict__ seql, float* __restrict__ h1)
{
  __shared__ __align__(16) float xs[8 * D1];
  const int t   = threadIdx.x;
  const int ctl = blockIdx.x;      // 0..3
  const int rg  = blockIdx.y;      // 0..31
  const int mod = blockIdx.z;
  const float* feats = mod ? txt : img;
  const float* W1    = mod ? W1t : W1i;
  const float* b1    = mod ? b1t : b1i;
  const int rowbase = rg * 8;

  float4* xs4 = reinterpret_cast<float4*>(xs);
  for (int fi = t; fi < 8 * D1 / 4; fi += 256){
    int r  = fi / (D1 / 4);
    int c4 = fi % (D1 / 4);
    int b  = rowbase + r;
    int last = seql[b];
    xs4[fi] = reinterpret_cast<const float4*>(feats + (size_t)(b * Lq + last) * D1)[c4];
  }
  __syncthreads();

  const int tc = t & 63, tr = t >> 6;
  const int r0 = tr * 2, r1 = tr * 2 + 1;
  const int c  = ctl * 256 + tc * 4;
  float4 a0 = {0,0,0,0}, a1 = {0,0,0,0};
  const float4* W4  = reinterpret_cast<const float4*>(W1);
  const float4* x40 = reinterpret_cast<const float4*>(xs + r0 * D1);
  const float4* x41 = reinterpret_cast<const float4*>(xs + r1 * D1);
  const int cq = c >> 2;
#pragma unroll 2
  for (int d = 0; d < D1; d += 4){
    float4 xv0 = x40[d >> 2];
    float4 xv1 = x41[d >> 2];
    float4 w0 = W4[(size_t)(d + 0) * (Hh / 4) + cq];
    float4 w1 = W4[(size_t)(d + 1) * (Hh / 4) + cq];
    float4 w2 = W4[(size_t)(d + 2) * (Hh / 4) + cq];
    float4 w3 = W4[(size_t)(d + 3) * (Hh / 4) + cq];
    fma4(a0, xv0.x, w0); fma4(a0, xv0.y, w1); fma4(a0, xv0.z, w2); fma4(a0, xv0.w, w3);
    fma4(a1, xv1.x, w0); fma4(a1, xv1.y, w1); fma4(a1, xv1.z, w2); fma4(a1, xv1.w, w3);
  }
  float4 bb = reinterpret_cast<const float4*>(b1)[cq];
  a0.x += bb.x; a0.y += bb.y; a0.z += bb.z; a0.w += bb.w;
  a1.x += bb.x; a1.y += bb.y; a1.z += bb.z; a1.w += bb.w;
  float4* out4 = reinterpret_cast<float4*>(h1);
  out4[((size_t)(mod * Bb + rowbase + r0) * Hh + c) >> 2] = a0;
  out4[((size_t)(mod * Bb + rowbase + r1) * Hh + c) >> 2] = a1;
}

// ---------------- K2: LN + gelu + GEMM2 + reparam-z + KL ----------------
// grid (128 pairs, 2 mods), 256 threads; 2 rows per block (128 threads per row)
__global__ __launch_bounds__(256) void k_enc_gemm2(
    const float* __restrict__ h1,
    const float* __restrict__ gi, const float* __restrict__ gt,
    const float* __restrict__ bei, const float* __restrict__ bet,
    const float* __restrict__ W2i, const float* __restrict__ W2t,
    const float* __restrict__ b2i, const float* __restrict__ b2t,
    const float* __restrict__ epsi, const float* __restrict__ epst,
    const int* __restrict__ seql,
    float* __restrict__ zout, float* __restrict__ kl)
{
  __shared__ __align__(16) float hsh[2 * Hh];
  __shared__ float2 red[256];
  const int t = threadIdx.x;
  const int pair = blockIdx.x, mod = blockIdx.y;
  const int rt = t >> 7, T = t & 127;
  const int b = pair * 2 + rt;
  const float* g   = mod ? gt  : gi;
  const float* be  = mod ? bet : bei;
  const float* W2  = mod ? W2t : W2i;
  const float* b2  = mod ? b2t : b2i;
  const float* eps = mod ? epst : epsi;

  const float4* h14 = reinterpret_cast<const float4*>(h1 + (size_t)(mod * Bb + b) * Hh);
  float4 hv0 = h14[T * 2], hv1 = h14[T * 2 + 1];
  float ps = hv0.x + hv0.y + hv0.z + hv0.w + hv1.x + hv1.y + hv1.z + hv1.w;
  float pq = hv0.x*hv0.x + hv0.y*hv0.y + hv0.z*hv0.z + hv0.w*hv0.w
           + hv1.x*hv1.x + hv1.y*hv1.y + hv1.z*hv1.z + hv1.w*hv1.w;
  red[t] = make_float2(ps, pq);
  __syncthreads();
  for (int s = 64; s; s >>= 1){
    if (T < s){ red[t].x += red[t + s].x; red[t].y += red[t + s].y; }
    __syncthreads();
  }
  float2 tot = red[rt << 7];
  float mean = tot.x * (1.0f / Hh);
  float var  = tot.y * (1.0f / Hh) - mean * mean;
  float rstd = rsqrtf(var + 1e-5f);

  {
    const float4* g4  = reinterpret_cast<const float4*>(g);
    const float4* be4 = reinterpret_cast<const float4*>(be);
    float4 ga = g4[T*2], gb = g4[T*2+1], ba = be4[T*2], bb = be4[T*2+1];
    float hv[8] = {hv0.x,hv0.y,hv0.z,hv0.w, hv1.x,hv1.y,hv1.z,hv1.w};
    float gg[8] = {ga.x,ga.y,ga.z,ga.w, gb.x,gb.y,gb.z,gb.w};
    float bv[8] = {ba.x,ba.y,ba.z,ba.w, bb.x,bb.y,bb.z,bb.w};
#pragma unroll
    for (int k = 0; k < 8; k++){
      float v = (hv[k] - mean) * rstd * gg[k] + bv[k];
      hsh[rt * Hh + T * 8 + k] = gelu_exact(v);
    }
  }
  __syncthreads();

  float4 acc = {0,0,0,0};
  const float4* W24 = reinterpret_cast<const float4*>(W2);
  const float4* hh4 = reinterpret_cast<const float4*>(hsh + rt * Hh);
#pragma unroll 2
  for (int d = 0; d < Hh; d += 4){
    float4 hv4 = hh4[d >> 2];
    float4 w0 = W24[(size_t)(d + 0) * (K2v / 4) + T];
    float4 w1 = W24[(size_t)(d + 1) * (K2v / 4) + T];
    float4 w2 = W24[(size_t)(d + 2) * (K2v / 4) + T];
    float4 w3 = W24[(size_t)(d + 3) * (K2v / 4) + T];
    fma4(acc, hv4.x, w0); fma4(acc, hv4.y, w1); fma4(acc, hv4.z, w2); fma4(acc, hv4.w, w3);
  }
  float4 b2v = reinterpret_cast<const float4*>(b2)[T];
  acc.x += b2v.x; acc.y += b2v.y; acc.z += b2v.z; acc.w += b2v.w;
  __syncthreads();                                 // everyone done reading hsh
  reinterpret_cast<float4*>(hsh + rt * K2v)[T] = acc;   // params row
  __syncthreads();

  if (T < 64){
    float4 mu = reinterpret_cast<const float4*>(hsh + rt * K2v)[T];
    float4 lv = reinterpret_cast<const float4*>(hsh + rt * K2v + Kk)[T];
    int last = seql[b];
    float4 ev = reinterpret_cast<const float4*>(eps + (size_t)(b * Lq + last) * Kk)[T];
    float zr0 = mu.x + ev.x * expf(0.5f * lv.x);
    float zr1 = mu.y + ev.y * expf(0.5f * lv.y);
    float zr2 = mu.z + ev.z * expf(0.5f * lv.z);
    float zr3 = mu.w + ev.w * expf(0.5f * lv.w);
    float s2 = zr0*zr0 + zr1*zr1 + zr2*zr2 + zr3*zr3;
    float klp = (1.0f + lv.x - mu.x*mu.x - expf(lv.x))
              + (1.0f + lv.y - mu.y*mu.y - expf(lv.y))
              + (1.0f + lv.z - mu.z*mu.z - expf(lv.z))
              + (1.0f + lv.w - mu.w*mu.w - expf(lv.w));
    float s2t = wred(s2);
    float klt = wred(klp);
    float inv = 1.0f / fmaxf(sqrtf(s2t), 1e-12f);
    float4 zv = {zr0*inv, zr1*inv, zr2*inv, zr3*inv};
    reinterpret_cast<float4*>(zout + (size_t)(mod * Bb + b) * Kk)[T] = zv;
    if (T == 0) atomicAdd(kl + mod, -0.5f * klt);
  }
}

// ---------------- K3: fused score-MLP  z -> score (+ ysy for txt) ----------------
__global__ __launch_bounds__(256) void k_sc(
    const float* __restrict__ z,
    const float* __restrict__ W1a, const float* __restrict__ W1b,
    const float* __restrict__ b1a, const float* __restrict__ b1b,
    const float* __restrict__ ga,  const float* __restrict__ gb,
    const float* __restrict__ bea, const float* __restrict__ beb,
    const float* __restrict__ W2a, const float* __restrict__ W2b,
    const float* __restrict__ b2a, const float* __restrict__ b2b,
    float* __restrict__ score, float* __restrict__ ysy)
{
  __shared__ __align__(16) float zsh[2 * Kk];
  __shared__ __align__(16) float hsh[2 * K2v];
  __shared__ float2 red[256];
  const int t = threadIdx.x;
  const int pair = blockIdx.x, mod = blockIdx.y;
  const int rt = t >> 7, T = t & 127;
  const int b = pair * 2 + rt;
  const float* W1 = mod ? W1b : W1a;
  const float* b1 = mod ? b1b : b1a;
  const float* g  = mod ? gb  : ga;
  const float* be = mod ? beb : bea;
  const float* W2 = mod ? W2b : W2a;
  const float* b2 = mod ? b2b : b2a;

  const size_t zbase = (size_t)(mod * Bb + pair * 2) * Kk;
  zsh[t]       = z[zbase + t];
  zsh[t + 256] = z[zbase + t + 256];
  __syncthreads();

  // GEMM1: (256) @ (256,512)
  float4 acc = {0,0,0,0};
  const float4* W14 = reinterpret_cast<const float4*>(W1);
  const float4* z4  = reinterpret_cast<const float4*>(zsh + rt * Kk);
#pragma unroll 2
  for (int d = 0; d < Kk; d += 4){
    float4 zv = z4[d >> 2];
    float4 w0 = W14[(size_t)(d + 0) * (K2v / 4) + T];
    float4 w1 = W14[(size_t)(d + 1) * (K2v / 4) + T];
    float4 w2 = W14[(size_t)(d + 2) * (K2v / 4) + T];
    float4 w3 = W14[(size_t)(d + 3) * (K2v / 4) + T];
    fma4(acc, zv.x, w0); fma4(acc, zv.y, w1); fma4(acc, zv.z, w2); fma4(acc, zv.w, w3);
  }
  float4 b1v = reinterpret_cast<const float4*>(b1)[T];
  acc.x += b1v.x; acc.y += b1v.y; acc.z += b1v.z; acc.w += b1v.w;

  // LN over 512
  float ps = acc.x + acc.y + acc.z + acc.w;
  float pq = acc.x*acc.x + acc.y*acc.y + acc.z*acc.z + acc.w*acc.w;
  red[t] = make_float2(ps, pq);
  __syncthreads();
  for (int s = 64; s; s >>= 1){
    if (T < s){ red[t].x += red[t + s].x; red[t].y += red[t + s].y; }
    __syncthreads();
  }
  float2 tot = red[rt << 7];
  float mean = tot.x * (1.0f / K2v);
  float var  = tot.y * (1.0f / K2v) - mean * mean;
  float rstd = rsqrtf(var + 1e-5f);
  float4 gv  = reinterpret_cast<const float4*>(g)[T];
  float4 bev = reinterpret_cast<const float4*>(be)[T];
  float4 h;
  h.x = gelu_exact((acc.x - mean) * rstd * gv.x + bev.x);
  h.y = gelu_exact((acc.y - mean) * rstd * gv.y + bev.y);
  h.z = gelu_exact((acc.z - mean) * rstd * gv.z + bev.z);
  h.w = gelu_exact((acc.w - mean) * rstd * gv.w + bev.w);
  reinterpret_cast<float4*>(hsh + rt * K2v)[T] = h;
  __syncthreads();

  // GEMM2: (512) @ (512,256)
  float2 a2 = {0, 0};
  const float2* W22 = reinterpret_cast<const float2*>(W2);
  const float4* h4  = reinterpret_cast<const float4*>(hsh + rt * K2v);
#pragma unroll 2
  for (int d = 0; d < K2v; d += 4){
    float4 hv = h4[d >> 2];
    float2 w0 = W22[(size_t)(d + 0) * (Kk / 2) + T];
    float2 w1 = W22[(size_t)(d + 1) * (Kk / 2) + T];
    float2 w2 = W22[(size_t)(d + 2) * (Kk / 2) + T];
    float2 w3 = W22[(size_t)(d + 3) * (Kk / 2) + T];
    a2.x += hv.x*w0.x + hv.y*w1.x + hv.z*w2.x + hv.w*w3.x;
    a2.y += hv.x*w0.y + hv.y*w1.y + hv.z*w2.y + hv.w*w3.y;
  }
  float2 b2v = reinterpret_cast<const float2*>(b2)[T];
  a2.x += b2v.x; a2.y += b2v.y;
  reinterpret_cast<float2*>(score + (size_t)(mod * Bb + b) * Kk)[T] = a2;

  // ysy = dot(txt_z_row, txt_score_row), needed for score-kernel term2
  float yp = zsh[rt * Kk + T * 2] * a2.x + zsh[rt * Kk + T * 2 + 1] * a2.y;
  __syncthreads();
  red[t].x = yp;
  __syncthreads();
  for (int s = 64; s; s >>= 1){
    if (T < s) red[t].x += red[t + s].x;
    __syncthreads();
  }
  if (mod == 1 && T == 0) ysy[b] = red[rt << 7].x;
}

// ---------------- K4: pairwise dist_sq between img_z and txt_z ----------------
__global__ __launch_bounds__(256) void k_dist(const float* __restrict__ z, float* __restrict__ dist){
  __shared__ __align__(16) float xsh[Kk];
  const int i = blockIdx.x, j = threadIdx.x;
  xsh[j] = z[(size_t)i * Kk + j];
  __syncthreads();
  const float4* y4 = reinterpret_cast<const float4*>(z + (size_t)Bb * Kk);
  const float4* x4 = reinterpret_cast<const float4*>(xsh);
  float acc = 0.0f;
#pragma unroll 4
  for (int d = 0; d < Kk; d += 4){
    float4 xv = x4[d >> 2];
    float4 yv = y4[j * (Kk / 4) + (d >> 2)];
    float d0 = xv.x - yv.x, d1 = xv.y - yv.y, d2 = xv.z - yv.z, d3 = xv.w - yv.w;
    acc += d0*d0 + d1*d1 + d2*d2 + d3*d3;
  }
  dist[i * 256 + j] = acc;
}

// ---------------- K5: exact median (ranks 32767/32768) via bit binary search ----------------
__global__ __launch_bounds__(1024) void k_median(const float* __restrict__ dist, float* __restrict__ scal){
  __shared__ int redc[2][16];
  const int t = threadIdx.x;
  unsigned u[64];
#pragma unroll
  for (int k = 0; k < 64; k++) u[k] = __float_as_uint(dist[k * 1024 + t]);  // nonneg -> monotone bits

  unsigned lo0 = 0, hi0 = 0xFFFFFFFFu, lo1 = 0, hi1 = 0xFFFFFFFFu;
  for (int it = 0; it < 32; ++it){
    unsigned mid0 = lo0 + ((hi0 - lo0) >> 1);
    unsigned mid1 = lo1 + ((hi1 - lo1) >> 1);
    int c0 = 0, c1 = 0;
#pragma unroll
    for (int k = 0; k < 64; k++){ c0 += (u[k] <= mid0); c1 += (u[k] <= mid1); }
    c0 = wredi(c0); c1 = wredi(c1);
    const int w = t >> 6;
    if (!(t & 63)){ redc[0][w] = c0; redc[1][w] = c1; }
    __syncthreads();
    if (t == 0){
      int s0 = 0, s1 = 0;
#pragma unroll
      for (int i = 0; i < 16; i++){ s0 += redc[0][i]; s1 += redc[1][i]; }
      redc[0][0] = s0; redc[1][0] = s1;
    }
    __syncthreads();
    int tot0 = redc[0][0], tot1 = redc[1][0];
    __syncthreads();
    if (tot0 >= 32768) hi0 = mid0; else lo0 = mid0 + 1;
    if (tot1 >= 32769) hi1 = mid1; else lo1 = mid1 + 1;
  }
  if (t == 0){
    float med = 0.5f * (__uint_as_float(lo0) + __uint_as_float(lo1));
    float bw  = sqrtf(med * 0.5f);              // BW_FACTOR = 1
    bw = fminf(fmaxf(bw, 0.1f), 10.0f);
    scal[3] = bw * bw;
  }
}

// ---------------- K6: score-kernel reduction ----------------
__global__ __launch_bounds__(256) void k_score(
    const float* __restrict__ z, const float* __restrict__ score,
    const float* __restrict__ ysy, const float* __restrict__ scal,
    float* __restrict__ alignv)
{
  __shared__ __align__(16) float xsh[Kk];
  __shared__ __align__(16) float sxsh[Kk];
  __shared__ float red4[4];
  const int i = blockIdx.x, j = threadIdx.x;
  xsh[j]  = z[(size_t)i * Kk + j];
  sxsh[j] = score[(size_t)i * Kk + j];
  __syncthreads();
  const float bw2 = scal[3];
  const float4* y4  = reinterpret_cast<const float4*>(z + (size_t)Bb * Kk);
  const float4* sy4 = reinterpret_cast<const float4*>(score + (size_t)Bb * Kk);
  const float4* x4  = reinterpret_cast<const float4*>(xsh);
  const float4* sx4 = reinterpret_cast<const float4*>(sxsh);
  float xy = 0, ssy = 0, xsy = 0, y2 = 0, x2 = 0;
#pragma unroll 2
  for (int d = 0; d < Kk; d += 4){
    float4 xv  = x4[d >> 2];
    float4 sxv = sx4[d >> 2];
    float4 yv  = y4[j * (Kk / 4) + (d >> 2)];
    float4 syv = sy4[j * (Kk / 4) + (d >> 2)];
    xy  += xv.x*yv.x  + xv.y*yv.y  + xv.z*yv.z  + xv.w*yv.w;
    ssy += sxv.x*syv.x + sxv.y*syv.y + sxv.z*syv.z + sxv.w*syv.w;
    xsy += xv.x*syv.x + xv.y*syv.y + xv.z*syv.z + xv.w*syv.w;
    y2  += yv.x*yv.x  + yv.y*yv.y  + yv.z*yv.z  + yv.w*yv.w;
    x2  += xv.x*xv.x  + xv.y*xv.y  + xv.z*xv.z  + xv.w*xv.w;
  }
  float d2 = fmaxf(x2 + y2 - 2.0f * xy, 0.0f);
  float kk = expf(-d2 / (2.0f * bw2));
  float t1 = kk * ssy;
  float t2 = (xsy - ysy[j]) * kk / bw2;
  float t3 = d2 * kk / (bw2 * bw2) - kk * (float)Kk / bw2;
  float s = wred(t1 + t2 + t3);
  if (!(j & 63)) red4[j >> 6] = s;
  __syncthreads();
  if (j == 0) atomicAdd(alignv, red4[0] + red4[1] + red4[2] + red4[3]);
}

// ---------------- K7: finalize ----------------
__global__ void k_final(const float* __restrict__ scal, float* __restrict__ out){
  if (threadIdx.x == 0){
    float kl_loss = 0.5f * (scal[0] + scal[1]) * (1.0f / 256.0f);
    out[0] = kl_loss + 0.1f * scal[2] * (1.0f / 65536.0f);
  }
}

extern "C" void kernel_launch(void* const* d_in, const int* in_sizes, int n_in,
                              void* d_out, int out_size, void* d_ws, size_t ws_size,
                              hipStream_t stream) {
  (void)in_sizes; (void)n_in; (void)out_size; (void)ws_size;
  const float* img  = (const float*)d_in[0];
  const float* txt  = (const float*)d_in[1];
  const float* epsi = (const float*)d_in[2];
  const float* epst = (const float*)d_in[3];
  const int*   mask = (const int*)d_in[4];
  const float* eW1i = (const float*)d_in[5];
  const float* eb1i = (const float*)d_in[6];
  const float* egi  = (const float*)d_in[7];
  const float* ebei = (const float*)d_in[8];
  const float* eW2i = (const float*)d_in[9];
  const float* eb2i = (const float*)d_in[10];
  const float* eW1t = (const float*)d_in[11];
  const float* eb1t = (const float*)d_in[12];
  const float* egt  = (const float*)d_in[13];
  const float* ebet = (const float*)d_in[14];
  const float* eW2t = (const float*)d_in[15];
  const float* eb2t = (const float*)d_in[16];
  const float* sW1i = (const float*)d_in[17];
  const float* sb1i = (const float*)d_in[18];
  const float* sgi  = (const float*)d_in[19];
  const float* sbei = (const float*)d_in[20];
  const float* sW2i = (const float*)d_in[21];
  const float* sb2i = (const float*)d_in[22];
  const float* sW1t = (const float*)d_in[23];
  const float* sb1t = (const float*)d_in[24];
  const float* sgt  = (const float*)d_in[25];
  const float* sbet = (const float*)d_in[26];
  const float* sW2t = (const float*)d_in[27];
  const float* sb2t = (const float*)d_in[28];

  float* ws   = (float*)d_ws;
  int*   seql = (int*)(ws + WS_SEQL);
  float* scal = ws + WS_SCAL;

  hipMemsetAsync(scal, 0, 4 * sizeof(float), stream);
  k_seqlast<<<1, 256, 0, stream>>>(mask, seql);
  k_enc_gemm1<<<dim3(4, 32, 2), 256, 0, stream>>>(img, txt, eW1i, eW1t, eb1i, eb1t, seql, ws + WS_H1);
  k_enc_gemm2<<<dim3(128, 2), 256, 0, stream>>>(ws + WS_H1, egi, egt, ebei, ebet,
                                                eW2i, eW2t, eb2i, eb2t, epsi, epst,
                                                seql, ws + WS_Z, scal);
  k_sc<<<dim3(128, 2), 256, 0, stream>>>(ws + WS_Z, sW1i, sW1t, sb1i, sb1t, sgi, sgt,
                                         sbei, sbet, sW2i, sW2t, sb2i, sb2t,
                                         ws + WS_SCORE, ws + WS_YSY);
  k_dist<<<256, 256, 0, stream>>>(ws + WS_Z, ws + WS_DIST);
  k_median<<<1, 1024, 0, stream>>>(ws + WS_DIST, scal);
  k_score<<<256, 256, 0, stream>>>(ws + WS_Z, ws + WS_SCORE, ws + WS_YSY, scal, scal + 2);
  k_final<<<1, 64, 0, stream>>>(scal, (float*)d_out);
}

// Round 2
// 152.307 us; speedup vs baseline: 1.7675x; 1.7675x over previous
//
#include <hip/hip_runtime.h>
#include <math.h>

#define Bb   256
#define Lq   128
#define D1   768
#define Hh   1024
#define Kk   256
#define K2v  512

// ---- ws layout (float offsets) ----
#define OFF_XG    0                         // 512*768
#define OFF_EPSG  393216                    // 512*256
#define OFF_P     524288                    // partial arena: 1572864 floats (max over GEMMs)
#define OFF_HACT  2097152                   // 512*1024 (reused as hact2 512*512)
#define OFF_Z     2621440                   // 512*256
#define OFF_SCORE 2752512                   // 512*256
#define OFF_DIST  2883584                   // 65536
#define OFF_HIST  2949120                   // 8192 ints
#define OFF_SCAL  2957312                   // [0]=kl_img [1]=kl_txt [2]=align [3]=bw2 (8 slots)
#define OFF_YSY   2957320                   // 512
#define OFF_SEQL  2957832                   // 256 ints
// total ~2.96M floats = 11.8 MB

__device__ __forceinline__ float wred(float v){
#pragma unroll
  for (int m = 32; m; m >>= 1) v += __shfl_xor(v, m, 64);
  return v;
}
__device__ __forceinline__ float gelu_exact(float x){
  return 0.5f * x * (1.0f + erff(x * 0.70710678118654752f));
}
__device__ __forceinline__ void fma4(float4& a, float s, const float4 w){
  a.x = fmaf(s, w.x, a.x); a.y = fmaf(s, w.y, a.y);
  a.z = fmaf(s, w.z, a.z); a.w = fmaf(s, w.w, a.w);
}

// ---------------- seq_last ----------------
__global__ void k_seqlast(const int* __restrict__ mask, int* __restrict__ seql){
  int b = threadIdx.x;
  const int4* m4 = reinterpret_cast<const int4*>(mask + b * Lq);
  int s = 0;
#pragma unroll
  for (int i = 0; i < Lq / 4; i++){ int4 v = m4[i]; s += v.x + v.y + v.z + v.w; }
  seql[b] = s - 1;
}

// ---------------- gather last rows of features + eps ----------------
__global__ __launch_bounds__(256) void k_gather(
    const float* __restrict__ img, const float* __restrict__ txt,
    const float* __restrict__ epsi, const float* __restrict__ epst,
    const int* __restrict__ seql, float* __restrict__ xg, float* __restrict__ epsg)
{
  int b = blockIdx.x, t = threadIdx.x;
  int last = seql[b];
  const float4* ir = reinterpret_cast<const float4*>(img + (size_t)(b*Lq + last) * D1);
  const float4* tr = reinterpret_cast<const float4*>(txt + (size_t)(b*Lq + last) * D1);
  float4* xi = reinterpret_cast<float4*>(xg + (size_t)b * D1);
  float4* xt = reinterpret_cast<float4*>(xg + (size_t)(Bb + b) * D1);
  if (t < D1/4){ xi[t] = ir[t]; xt[t] = tr[t]; }
  const float4* ei = reinterpret_cast<const float4*>(epsi + (size_t)(b*Lq + last) * Kk);
  const float4* et = reinterpret_cast<const float4*>(epst + (size_t)(b*Lq + last) * Kk);
  float4* gi = reinterpret_cast<float4*>(epsg + (size_t)b * Kk);
  float4* gt = reinterpret_cast<float4*>(epsg + (size_t)(Bb + b) * Kk);
  if (t < Kk/4){ gi[t] = ei[t]; gt[t] = et[t]; }
}

// ---------------- generic K-split GEMM: P[ks] = A_tile @ W_chunk (no bias) ----------------
// A row-major [512][LDA]; W row-major [K][N]; rows 0..255 use Wi, 256..511 use Wt.
// grid (N/TN, 512/TM, K/KCH), 256 threads.
template<int TM, int TN, int KCH, int N, int LDA>
__global__ __launch_bounds__(256) void k_gemm(
    const float* __restrict__ A, const float* __restrict__ Wi,
    const float* __restrict__ Wt, float* __restrict__ P)
{
  constexpr int CT  = TN / 4;        // col threads (32)
  constexpr int RT  = 256 / CT;      // row threads (8)
  constexpr int RPT = TM / RT;       // rows per thread (1 or 2)
  __shared__ __align__(16) float xs[TM * KCH];
  const int t   = threadIdx.x;
  const int ctl = blockIdx.x, rg = blockIdx.y, ks = blockIdx.z;
  const int r0  = rg * TM;
  const float* W = (r0 >= 256) ? Wt : Wi;
  const int kb  = ks * KCH;

  const float4* A4 = reinterpret_cast<const float4*>(A);
  float4* xs4 = reinterpret_cast<float4*>(xs);
  constexpr int TOT4 = TM * KCH / 4;
#pragma unroll
  for (int i = t; i < TOT4; i += 256){
    int rr = i / (KCH/4), cc = i % (KCH/4);
    xs4[i] = A4[(size_t)(r0 + rr) * (LDA/4) + (kb >> 2) + cc];
  }
  __syncthreads();

  const int c  = t % CT;
  const int rt = t / CT;
  const int cq = ctl * CT + c;       // float4 column index
  const float4* W4 = reinterpret_cast<const float4*>(W);
  float4 acc[RPT];
#pragma unroll
  for (int r = 0; r < RPT; r++) acc[r] = make_float4(0,0,0,0);

#pragma unroll 1
  for (int kk = 0; kk < KCH; kk += 8){
    float4 w[8];
#pragma unroll
    for (int u = 0; u < 8; u++) w[u] = W4[(size_t)(kb + kk + u) * (N/4) + cq];
#pragma unroll
    for (int u = 0; u < 8; u++){
#pragma unroll
      for (int r = 0; r < RPT; r++){
        float xv = xs[(rt + r*RT) * KCH + kk + u];
        fma4(acc[r], xv, w[u]);
      }
    }
  }
  float4* P4 = reinterpret_cast<float4*>(P);
#pragma unroll
  for (int r = 0; r < RPT; r++){
    int row = r0 + rt + r*RT;
    P4[((size_t)ks * 512 + row) * (N/4) + cq] = acc[r];
  }
}

// ---------------- LN+gelu over 1024-wide rows (sums 3 partials + bias) ----------------
__global__ __launch_bounds__(256) void k_ln1(
    const float* __restrict__ P,
    const float* __restrict__ b1i, const float* __restrict__ b1t,
    const float* __restrict__ gi,  const float* __restrict__ gt,
    const float* __restrict__ bei, const float* __restrict__ bet,
    float* __restrict__ hact)
{
  __shared__ float2 wsum[4];
  const int row = blockIdx.x, t = threadIdx.x;
  const float* b1 = row >= 256 ? b1t : b1i;
  const float* g  = row >= 256 ? gt  : gi;
  const float* be = row >= 256 ? bet : bei;
  const float4* P4 = reinterpret_cast<const float4*>(P);
  float4 v = make_float4(0,0,0,0);
#pragma unroll
  for (int s = 0; s < 3; s++){
    float4 p = P4[((size_t)s * 512 + row) * (Hh/4) + t];
    v.x += p.x; v.y += p.y; v.z += p.z; v.w += p.w;
  }
  float4 bb = reinterpret_cast<const float4*>(b1)[t];
  v.x += bb.x; v.y += bb.y; v.z += bb.z; v.w += bb.w;
  float ps = v.x + v.y + v.z + v.w;
  float pq = v.x*v.x + v.y*v.y + v.z*v.z + v.w*v.w;
  ps = wred(ps); pq = wred(pq);
  if (!(t & 63)) wsum[t >> 6] = make_float2(ps, pq);
  __syncthreads();
  float S = 0, Q = 0;
#pragma unroll
  for (int i = 0; i < 4; i++){ S += wsum[i].x; Q += wsum[i].y; }
  float mean = S * (1.0f/Hh);
  float var  = Q * (1.0f/Hh) - mean*mean;
  float rstd = rsqrtf(var + 1e-5f);
  float4 gv  = reinterpret_cast<const float4*>(g)[t];
  float4 bev = reinterpret_cast<const float4*>(be)[t];
  float4 h;
  h.x = gelu_exact((v.x - mean)*rstd*gv.x + bev.x);
  h.y = gelu_exact((v.y - mean)*rstd*gv.y + bev.y);
  h.z = gelu_exact((v.z - mean)*rstd*gv.z + bev.z);
  h.w = gelu_exact((v.w - mean)*rstd*gv.w + bev.w);
  reinterpret_cast<float4*>(hact)[(size_t)row * (Hh/4) + t] = h;
}

// ---------------- LN+gelu over 512-wide rows (sums 4 partials + bias) ----------------
__global__ __launch_bounds__(128) void k_ln2(
    const float* __restrict__ P,
    const float* __restrict__ b1i, const float* __restrict__ b1t,
    const float* __restrict__ gi,  const float* __restrict__ gt,
    const float* __restrict__ bei, const float* __restrict__ bet,
    float* __restrict__ hact2)
{
  __shared__ float2 wsum[2];
  const int row = blockIdx.x, t = threadIdx.x;
  const float* b1 = row >= 256 ? b1t : b1i;
  const float* g  = row >= 256 ? gt  : gi;
  const float* be = row >= 256 ? bet : bei;
  const float4* P4 = reinterpret_cast<const float4*>(P);
  float4 v = make_float4(0,0,0,0);
#pragma unroll
  for (int s = 0; s < 4; s++){
    float4 p = P4[((size_t)s * 512 + row) * (K2v/4) + t];
    v.x += p.x; v.y += p.y; v.z += p.z; v.w += p.w;
  }
  float4 bb = reinterpret_cast<const float4*>(b1)[t];
  v.x += bb.x; v.y += bb.y; v.z += bb.z; v.w += bb.w;
  float ps = v.x + v.y + v.z + v.w;
  float pq = v.x*v.x + v.y*v.y + v.z*v.z + v.w*v.w;
  ps = wred(ps); pq = wred(pq);
  if (!(t & 63)) wsum[t >> 6] = make_float2(ps, pq);
  __syncthreads();
  float S = wsum[0].x + wsum[1].x, Q = wsum[0].y + wsum[1].y;
  float mean = S * (1.0f/K2v);
  float var  = Q * (1.0f/K2v) - mean*mean;
  float rstd = rsqrtf(var + 1e-5f);
  float4 gv  = reinterpret_cast<const float4*>(g)[t];
  float4 bev = reinterpret_cast<const float4*>(be)[t];
  float4 h;
  h.x = gelu_exact((v.x - mean)*rstd*gv.x + bev.x);
  h.y = gelu_exact((v.y - mean)*rstd*gv.y + bev.y);
  h.z = gelu_exact((v.z - mean)*rstd*gv.z + bev.z);
  h.w = gelu_exact((v.w - mean)*rstd*gv.w + bev.w);
  reinterpret_cast<float4*>(hact2)[(size_t)row * (K2v/4) + t] = h;
}

// ---------------- reparam + normalize + KL (sums 4 partials + bias) ----------------
__global__ __launch_bounds__(64) void k_reparam(
    const float* __restrict__ P,
    const float* __restrict__ b2i, const float* __restrict__ b2t,
    const float* __restrict__ epsg, float* __restrict__ z, float* __restrict__ kl)
{
  const int row = blockIdx.x, t = threadIdx.x;
  const float* b2 = row >= 256 ? b2t : b2i;
  const float4* P4 = reinterpret_cast<const float4*>(P);
  float4 mu = make_float4(0,0,0,0), lv = make_float4(0,0,0,0);
#pragma unroll
  for (int s = 0; s < 4; s++){
    float4 a = P4[((size_t)s * 512 + row) * (K2v/4) + t];
    float4 c = P4[((size_t)s * 512 + row) * (K2v/4) + 64 + t];
    mu.x += a.x; mu.y += a.y; mu.z += a.z; mu.w += a.w;
    lv.x += c.x; lv.y += c.y; lv.z += c.z; lv.w += c.w;
  }
  float4 bm = reinterpret_cast<const float4*>(b2)[t];
  float4 bl = reinterpret_cast<const float4*>(b2)[64 + t];
  mu.x += bm.x; mu.y += bm.y; mu.z += bm.z; mu.w += bm.w;
  lv.x += bl.x; lv.y += bl.y; lv.z += bl.z; lv.w += bl.w;
  float4 ev = reinterpret_cast<const float4*>(epsg)[(size_t)row * 64 + t];
  float z0 = mu.x + ev.x * expf(0.5f * lv.x);
  float z1 = mu.y + ev.y * expf(0.5f * lv.y);
  float z2 = mu.z + ev.z * expf(0.5f * lv.z);
  float z3 = mu.w + ev.w * expf(0.5f * lv.w);
  float s2 = z0*z0 + z1*z1 + z2*z2 + z3*z3;
  float klp = (1.0f + lv.x - mu.x*mu.x - expf(lv.x))
            + (1.0f + lv.y - mu.y*mu.y - expf(lv.y))
            + (1.0f + lv.z - mu.z*mu.z - expf(lv.z))
            + (1.0f + lv.w - mu.w*mu.w - expf(lv.w));
  float s2t = wred(s2);
  float klt = wred(klp);
  float inv = 1.0f / fmaxf(sqrtf(s2t), 1e-12f);
  float4 zv = make_float4(z0*inv, z1*inv, z2*inv, z3*inv);
  reinterpret_cast<float4*>(z)[(size_t)row * 64 + t] = zv;
  if (t == 0) atomicAdd(kl + (row >= 256 ? 1 : 0), -0.5f * klt);
}

// ---------------- sum score partials + bias; ysy[row] = z_row . score_row ----------------
__global__ __launch_bounds__(64) void k_sum2(
    const float* __restrict__ P,
    const float* __restrict__ b2i, const float* __restrict__ b2t,
    const float* __restrict__ z, float* __restrict__ score, float* __restrict__ ysy)
{
  const int row = blockIdx.x, t = threadIdx.x;
  const float* b2 = row >= 256 ? b2t : b2i;
  const float4* P4 = reinterpret_cast<const float4*>(P);
  float4 v = make_float4(0,0,0,0);
#pragma unroll
  for (int s = 0; s < 4; s++){
    float4 p = P4[((size_t)s * 512 + row) * (Kk/4) + t];
    v.x += p.x; v.y += p.y; v.z += p.z; v.w += p.w;
  }
  float4 bb = reinterpret_cast<const float4*>(b2)[t];
  v.x += bb.x; v.y += bb.y; v.z += bb.z; v.w += bb.w;
  reinterpret_cast<float4*>(score)[(size_t)row * 64 + t] = v;
  float4 zv = reinterpret_cast<const float4*>(z)[(size_t)row * 64 + t];
  float yp = zv.x*v.x + zv.y*v.y + zv.z*v.z + zv.w*v.w;
  yp = wred(yp);
  if (t == 0) ysy[row] = yp;
}

// ---------------- pairwise dist_sq + 8192-bin histogram ----------------
__global__ __launch_bounds__(256) void k_dist(const float* __restrict__ z,
                                              float* __restrict__ dist, int* __restrict__ ghist){
  __shared__ __align__(16) float xsh[Kk];
  __shared__ int hl[8192];
  const int i = blockIdx.x, j = threadIdx.x;
  xsh[j] = z[(size_t)i * Kk + j];
#pragma unroll
  for (int k = j; k < 8192; k += 256) hl[k] = 0;
  __syncthreads();
  const float4* y4 = reinterpret_cast<const float4*>(z + (size_t)Bb * Kk);
  const float4* x4 = reinterpret_cast<const float4*>(xsh);
  float acc = 0.0f;
#pragma unroll 4
  for (int d = 0; d < Kk; d += 4){
    float4 xv = x4[d >> 2];
    float4 yv = y4[j * (Kk/4) + (d >> 2)];
    float d0 = xv.x - yv.x, d1 = xv.y - yv.y, d2 = xv.z - yv.z, d3 = xv.w - yv.w;
    acc += d0*d0 + d1*d1 + d2*d2 + d3*d3;
  }
  dist[i * 256 + j] = acc;
  int bin = (int)(acc * 2048.0f);
  bin = bin < 0 ? 0 : (bin > 8191 ? 8191 : bin);
  atomicAdd(&hl[bin], 1);
  __syncthreads();
  for (int k = j; k < 8192; k += 256){
    int c = hl[k];
    if (c) atomicAdd(ghist + k, c);
  }
}

// ---------------- bandwidth from histogram (ranks 32768, 32769 of 65536) ----------------
__global__ __launch_bounds__(256) void k_bw(const int* __restrict__ ghist, float* __restrict__ scal){
  __shared__ int wt[4];
  __shared__ int bres[2];
  const int t = threadIdx.x, lane = t & 63, w = t >> 6;
  const int base = t * 32;
  int s = 0;
#pragma unroll
  for (int u = 0; u < 32; u++) s += ghist[base + u];
  int sc = s;
#pragma unroll
  for (int m = 1; m < 64; m <<= 1){
    int o = __shfl_up(sc, m, 64);
    if (lane >= m) sc += o;
  }
  if (lane == 63) wt[w] = sc;
  __syncthreads();
  int off = 0;
  for (int i = 0; i < w; i++) off += wt[i];
  int cum = sc + off;
  int basex = cum - s;
#pragma unroll
  for (int rr = 0; rr < 2; rr++){
    int rank = 32768 + rr;
    if (basex < rank && cum >= rank){
      int c = basex;
      for (int u = 0; u < 32; u++){
        c += ghist[base + u];
        if (c >= rank){ bres[rr] = base + u; break; }
      }
    }
  }
  __syncthreads();
  if (t == 0){
    float vA = (bres[0] + 0.5f) * (1.0f / 2048.0f);
    float vB = (bres[1] + 0.5f) * (1.0f / 2048.0f);
    float med = 0.5f * (vA + vB);
    float bw = sqrtf(med * 0.5f);
    bw = fminf(fmaxf(bw, 0.1f), 10.0f);
    scal[3] = bw * bw;
  }
}

// ---------------- score-kernel reduction ----------------
__global__ __launch_bounds__(256) void k_score(
    const float* __restrict__ z, const float* __restrict__ score,
    const float* __restrict__ dist, const float* __restrict__ ysy,
    const float* __restrict__ scal, float* __restrict__ alignv)
{
  __shared__ __align__(16) float xsh[Kk];
  __shared__ __align__(16) float sxsh[Kk];
  __shared__ float red4[4];
  const int i = blockIdx.x, j = threadIdx.x;
  xsh[j]  = z[(size_t)i * Kk + j];
  sxsh[j] = score[(size_t)i * Kk + j];
  __syncthreads();
  const float bw2 = scal[3];
  const float4* sy4 = reinterpret_cast<const float4*>(score + (size_t)Bb * Kk);
  const float4* x4  = reinterpret_cast<const float4*>(xsh);
  const float4* sx4 = reinterpret_cast<const float4*>(sxsh);
  float ssy = 0, xsy = 0;
#pragma unroll 4
  for (int d = 0; d < Kk; d += 4){
    float4 xv  = x4[d >> 2];
    float4 sxv = sx4[d >> 2];
    float4 syv = sy4[j * (Kk/4) + (d >> 2)];
    ssy += sxv.x*syv.x + sxv.y*syv.y + sxv.z*syv.z + sxv.w*syv.w;
    xsy += xv.x*syv.x + xv.y*syv.y + xv.z*syv.z + xv.w*syv.w;
  }
  float d2 = dist[i * 256 + j];
  float kk = expf(-d2 / (2.0f * bw2));
  float t1 = kk * ssy;
  float t2 = (xsy - ysy[Bb + j]) * kk / bw2;
  float t3 = d2 * kk / (bw2 * bw2) - kk * (float)Kk / bw2;
  float s = wred(t1 + t2 + t3);
  if (!(j & 63)) red4[j >> 6] = s;
  __syncthreads();
  if (j == 0) atomicAdd(alignv, red4[0] + red4[1] + red4[2] + red4[3]);
}

// ---------------- finalize ----------------
__global__ void k_final(const float* __restrict__ scal, float* __restrict__ out){
  if (threadIdx.x == 0){
    float kl_loss = 0.5f * (scal[0] + scal[1]) * (1.0f / 256.0f);
    out[0] = kl_loss + 0.1f * scal[2] * (1.0f / 65536.0f);
  }
}

extern "C" void kernel_launch(void* const* d_in, const int* in_sizes, int n_in,
                              void* d_out, int out_size, void* d_ws, size_t ws_size,
                              hipStream_t stream) {
  (void)in_sizes; (void)n_in; (void)out_size; (void)ws_size;
  const float* img  = (const float*)d_in[0];
  const float* txt  = (const float*)d_in[1];
  const float* epsi = (const float*)d_in[2];
  const float* epst = (const float*)d_in[3];
  const int*   mask = (const int*)d_in[4];
  const float* eW1i = (const float*)d_in[5];
  const float* eb1i = (const float*)d_in[6];
  const float* egi  = (const float*)d_in[7];
  const float* ebei = (const float*)d_in[8];
  const float* eW2i = (const float*)d_in[9];
  const float* eb2i = (const float*)d_in[10];
  const float* eW1t = (const float*)d_in[11];
  const float* eb1t = (const float*)d_in[12];
  const float* egt  = (const float*)d_in[13];
  const float* ebet = (const float*)d_in[14];
  const float* eW2t = (const float*)d_in[15];
  const float* eb2t = (const float*)d_in[16];
  const float* sW1i = (const float*)d_in[17];
  const float* sb1i = (const float*)d_in[18];
  const float* sgi  = (const float*)d_in[19];
  const float* sbei = (const float*)d_in[20];
  const float* sW2i = (const float*)d_in[21];
  const float* sb2i = (const float*)d_in[22];
  const float* sW1t = (const float*)d_in[23];
  const float* sb1t = (const float*)d_in[24];
  const float* sgt  = (const float*)d_in[25];
  const float* sbet = (const float*)d_in[26];
  const float* sW2t = (const float*)d_in[27];
  const float* sb2t = (const float*)d_in[28];

  float* ws    = (float*)d_ws;
  float* xg    = ws + OFF_XG;
  float* epsg  = ws + OFF_EPSG;
  float* P     = ws + OFF_P;
  float* hact  = ws + OFF_HACT;   // also hact2
  float* z     = ws + OFF_Z;
  float* score = ws + OFF_SCORE;
  float* dist  = ws + OFF_DIST;
  int*   ghist = (int*)(ws + OFF_HIST);
  float* scal  = ws + OFF_SCAL;
  float* ysy   = ws + OFF_YSY;
  int*   seql  = (int*)(ws + OFF_SEQL);

  // zero hist (8192 ints) + scal (8 floats) — contiguous
  hipMemsetAsync(ghist, 0, (8192 + 8) * sizeof(float), stream);

  k_seqlast<<<1, 256, 0, stream>>>(mask, seql);
  k_gather<<<256, 256, 0, stream>>>(img, txt, epsi, epst, seql, xg, epsg);

  // enc GEMM1: xg[512,768] @ W1[768,1024], K-split 3
  k_gemm<16,128,256,1024,768><<<dim3(8,32,3), 256, 0, stream>>>(xg, eW1i, eW1t, P);
  k_ln1<<<512, 256, 0, stream>>>(P, eb1i, eb1t, egi, egt, ebei, ebet, hact);

  // enc GEMM2: hact[512,1024] @ W2[1024,512], K-split 4
  k_gemm<8,128,256,512,1024><<<dim3(4,64,4), 256, 0, stream>>>(hact, eW2i, eW2t, P);
  k_reparam<<<512, 64, 0, stream>>>(P, eb2i, eb2t, epsg, z, scal);

  // sc GEMM1: z[512,256] @ W1[256,512], K-split 4
  k_gemm<16,128,64,512,256><<<dim3(4,32,4), 256, 0, stream>>>(z, sW1i, sW1t, P);
  k_ln2<<<512, 128, 0, stream>>>(P, sb1i, sb1t, sgi, sgt, sbei, sbet, hact);

  // sc GEMM2: hact2[512,512] @ W2[512,256], K-split 4
  k_gemm<8,128,128,256,512><<<dim3(2,64,4), 256, 0, stream>>>(hact, sW2i, sW2t, P);
  k_sum2<<<512, 64, 0, stream>>>(P, sb2i, sb2t, z, score, ysy);

  k_dist<<<256, 256, 0, stream>>>(z, dist, ghist);
  k_bw<<<1, 256, 0, stream>>>(ghist, scal);
  k_score<<<256, 256, 0, stream>>>(z, score, dist, ysy, scal, scal + 2);
  k_final<<<1, 64, 0, stream>>>(scal, (float*)d_out);
}

// Round 3
// 94.940 us; speedup vs baseline: 2.8354x; 1.6042x over previous
//
#include <hip/hip_runtime.h>
#include <math.h>

#define Bb   256
#define Lq   128
#define D1   768
#define Hh   1024
#define Kk   256
#define K2v  512

// ---- ws float offsets ----
#define OFF_EPSG  0                    // 512*256
#define OFF_P     131072               // 2097152 floats (max partial arena)
#define OFF_Z     2228224              // 512*256
#define OFF_SCORE 2359296              // 512*256
#define OFF_DIST  2490368              // 65536
#define OFF_HIST  2555904              // 8192 ints
#define OFF_SCAL  2564096              // [0]=kl_i [1]=kl_t [2]=align [3]=spare [4]=counter
#define OFF_YSY   2564104              // 512
#define OFF_SEQL  2564616              // 256 ints
#define OFF_BF    2564880              // ushort arena below (16B aligned)

// ---- ushort offsets inside bf arena ----
#define UB_XG   0                      // 512*768
#define UB_HACT 393216                 // 512*1024 (reused as 512*512)
#define UB_ZB   917504                 // 512*256
#define UB_WT   1048576                // transposed bf16 weights, 3145728 ushort
#define WT_EW1I 0
#define WT_EW1T 786432
#define WT_EW2I 1572864
#define WT_EW2T 2097152
#define WT_SW1I 2621440
#define WT_SW1T 2752512
#define WT_SW2I 2883584
#define WT_SW2T 3014656

typedef __attribute__((ext_vector_type(8))) short short8v;
typedef __attribute__((ext_vector_type(4))) float f32x4;

__device__ __forceinline__ float wred(float v){
#pragma unroll
  for (int m = 32; m; m >>= 1) v += __shfl_xor(v, m, 64);
  return v;
}
__device__ __forceinline__ float gelu_exact(float x){
  return 0.5f * x * (1.0f + erff(x * 0.70710678118654752f));
}
__device__ __forceinline__ ushort f2b(float f){
  union { float f; unsigned u; } v; v.f = f;
  return (ushort)((v.u + 0x7FFFu + ((v.u >> 16) & 1u)) >> 16);
}

// ---------------- K0: zero hist/scal + seq_last ----------------
__global__ __launch_bounds__(256) void k_init(const int* __restrict__ mask,
                                              int* __restrict__ seql,
                                              int* __restrict__ ghist,
                                              float* __restrict__ scal){
  const int t = threadIdx.x, b = blockIdx.x;
  if (b == 0){
    const int4* m4 = reinterpret_cast<const int4*>(mask + t * Lq);
    int s = 0;
#pragma unroll
    for (int i = 0; i < Lq/4; i++){ int4 v = m4[i]; s += v.x + v.y + v.z + v.w; }
    seql[t] = s - 1;
  } else {
    reinterpret_cast<int4*>(ghist)[(b-1)*256 + t] = make_int4(0,0,0,0);
    if (b == 1 && t < 8) scal[t] = 0.0f;
  }
}

// ---------------- K1: gather rows (x -> bf16, eps f32) + weight transpose-convert ----------------
__global__ __launch_bounds__(256) void k_gather_conv(
    const float* __restrict__ img, const float* __restrict__ txt,
    const float* __restrict__ epsi, const float* __restrict__ epst,
    const int* __restrict__ seql,
    const float* __restrict__ eW1i, const float* __restrict__ eW1t,
    const float* __restrict__ eW2i, const float* __restrict__ eW2t,
    const float* __restrict__ sW1i, const float* __restrict__ sW1t,
    const float* __restrict__ sW2i, const float* __restrict__ sW2t,
    ushort* __restrict__ xgb, float* __restrict__ epsg, ushort* __restrict__ wt)
{
  __shared__ float lsf[32][33];
  const int bid = blockIdx.x, t = threadIdx.x;
  if (bid < 256){
    const int b = bid, last = seql[b];
    const float4* ir = reinterpret_cast<const float4*>(img + (size_t)(b*Lq+last)*D1);
    const float4* tr = reinterpret_cast<const float4*>(txt + (size_t)(b*Lq+last)*D1);
    if (t < 192){
      float4 v = ir[t];
      ushort4 o; o.x=f2b(v.x); o.y=f2b(v.y); o.z=f2b(v.z); o.w=f2b(v.w);
      reinterpret_cast<ushort4*>(xgb + (size_t)b*D1)[t] = o;
      float4 w = tr[t];
      ushort4 p; p.x=f2b(w.x); p.y=f2b(w.y); p.z=f2b(w.z); p.w=f2b(w.w);
      reinterpret_cast<ushort4*>(xgb + (size_t)(Bb+b)*D1)[t] = p;
    }
    if (t < 64){
      reinterpret_cast<float4*>(epsg + (size_t)b*Kk)[t] =
        reinterpret_cast<const float4*>(epsi + (size_t)(b*Lq+last)*Kk)[t];
      reinterpret_cast<float4*>(epsg + (size_t)(Bb+b)*Kk)[t] =
        reinterpret_cast<const float4*>(epst + (size_t)(b*Lq+last)*Kk)[t];
    }
    return;
  }
  // weight transpose-convert: W[K][N] f32 -> WT[N][K] bf16, 32x32 tiles
  const int wb = bid - 256;
  const float* src; ushort* dst; int Kd, Nd, ti;
  if      (wb < 768){  src=eW1i; dst=wt+WT_EW1I; Kd=768;  Nd=1024; ti=wb; }
  else if (wb < 1536){ src=eW1t; dst=wt+WT_EW1T; Kd=768;  Nd=1024; ti=wb-768; }
  else if (wb < 2048){ src=eW2i; dst=wt+WT_EW2I; Kd=1024; Nd=512;  ti=wb-1536; }
  else if (wb < 2560){ src=eW2t; dst=wt+WT_EW2T; Kd=1024; Nd=512;  ti=wb-2048; }
  else if (wb < 2688){ src=sW1i; dst=wt+WT_SW1I; Kd=256;  Nd=512;  ti=wb-2560; }
  else if (wb < 2816){ src=sW1t; dst=wt+WT_SW1T; Kd=256;  Nd=512;  ti=wb-2688; }
  else if (wb < 2944){ src=sW2i; dst=wt+WT_SW2I; Kd=512;  Nd=256;  ti=wb-2816; }
  else               { src=sW2t; dst=wt+WT_SW2T; Kd=512;  Nd=256;  ti=wb-2944; }
  const int ntile = Nd / 32;
  const int k0 = (ti / ntile) * 32, n0 = (ti % ntile) * 32;
  const int r = t >> 3, q = t & 7;
  float4 v = reinterpret_cast<const float4*>(src + (size_t)(k0+r)*Nd + n0)[q];
  lsf[r][q*4+0]=v.x; lsf[r][q*4+1]=v.y; lsf[r][q*4+2]=v.z; lsf[r][q*4+3]=v.w;
  __syncthreads();
  ushort4 o;
  o.x = f2b(lsf[q*4+0][r]); o.y = f2b(lsf[q*4+1][r]);
  o.z = f2b(lsf[q*4+2][r]); o.w = f2b(lsf[q*4+3][r]);
  *reinterpret_cast<ushort4*>(dst + (size_t)(n0+r)*Kd + k0 + q*4) = o;
}

// ---------------- MFMA bf16 K-split GEMM ----------------
// A: [512][K] bf16 row-major. WT: [N][K] bf16 (transposed weights). Rows>=256 use WTt.
// Block: 256 thr = 4 waves, tile BM x 64, K-chunk KCH. P[ks][512][N] f32 partials.
template<int BM, int KCH, int N, int K>
__global__ __launch_bounds__(256) void k_mgemm(
    const ushort* __restrict__ A, const ushort* __restrict__ WTi,
    const ushort* __restrict__ WTt, float* __restrict__ P)
{
  constexpr int RPW = BM / 64;                 // 16-row frags per wave
  __shared__ ushort LS[(BM + 64) * 32];
  const int tid = threadIdx.x;
  const int lane = tid & 63, wid = tid >> 6;
  const int n0 = blockIdx.x * 64;
  const int r0 = blockIdx.y * BM;
  const int kb = blockIdx.z * KCH;
  const ushort* WT = (r0 >= 256) ? WTt : WTi;

  f32x4 acc[RPW][4];
#pragma unroll
  for (int s = 0; s < RPW; s++)
#pragma unroll
    for (int c = 0; c < 4; c++) acc[s][c] = (f32x4){0.f,0.f,0.f,0.f};

  const int l15 = lane & 15, kg = lane >> 4;
  const int rdswz = (kg * 16) ^ ((l15 & 3) << 4);   // swizzled k-byte offset

  for (int k0 = kb; k0 < kb + KCH; k0 += 32){
    __syncthreads();
    // stage (BM+64) rows x 64B, bank-swizzled
    constexpr int NCHK = (BM + 64) * 4;        // 16B chunks
#pragma unroll
    for (int i = 0; i < NCHK / 256; i++){
      const int q = (i * 256 + tid) * 16;
      const int row = q >> 6, koff = q & 63;
      const ushort* src = (row < BM)
          ? (A  + (size_t)(r0 + row) * K + k0)
          : (WT + (size_t)(n0 + row - BM) * K + k0);
      short8v v = *reinterpret_cast<const short8v*>(
          reinterpret_cast<const char*>(src) + koff);
      const int dq = (q & ~63) | (koff ^ ((row & 3) << 4));
      *reinterpret_cast<short8v*>(reinterpret_cast<char*>(LS) + dq) = v;
    }
    __syncthreads();
    const char* Ab = reinterpret_cast<const char*>(LS);
    const char* Bbp = reinterpret_cast<const char*>(LS + BM * 32);
    short8v ar[RPW], bc[4];
#pragma unroll
    for (int s = 0; s < RPW; s++){
      const int row = wid * (RPW * 16) + s * 16 + l15;
      ar[s] = *reinterpret_cast<const short8v*>(Ab + row * 64 + rdswz);
    }
#pragma unroll
    for (int c = 0; c < 4; c++){
      const int col = c * 16 + l15;
      bc[c] = *reinterpret_cast<const short8v*>(Bbp + col * 64 + rdswz);
    }
#pragma unroll
    for (int s = 0; s < RPW; s++)
#pragma unroll
      for (int c = 0; c < 4; c++)
        acc[s][c] = __builtin_amdgcn_mfma_f32_16x16x32_bf16(ar[s], bc[c], acc[s][c], 0, 0, 0);
  }
  const int ks = blockIdx.z;
#pragma unroll
  for (int s = 0; s < RPW; s++)
#pragma unroll
    for (int c = 0; c < 4; c++)
#pragma unroll
      for (int r = 0; r < 4; r++){
        const int row = r0 + wid * (RPW * 16) + s * 16 + kg * 4 + r;
        const int col = n0 + c * 16 + l15;
        P[((size_t)ks * 512 + row) * N + col] = acc[s][c][r];
      }
}

// ---------------- LN+gelu 1024-wide (sum 4 partials + bias) -> bf16 ----------------
__global__ __launch_bounds__(256) void k_ln1(
    const float* __restrict__ P,
    const float* __restrict__ b1i, const float* __restrict__ b1t,
    const float* __restrict__ gi,  const float* __restrict__ gt,
    const float* __restrict__ bei, const float* __restrict__ bet,
    ushort* __restrict__ hb)
{
  __shared__ float2 wsum[4];
  const int row = blockIdx.x, t = threadIdx.x;
  const float* b1 = row >= 256 ? b1t : b1i;
  const float* g  = row >= 256 ? gt  : gi;
  const float* be = row >= 256 ? bet : bei;
  const float4* P4 = reinterpret_cast<const float4*>(P);
  float4 v = make_float4(0,0,0,0);
#pragma unroll
  for (int s = 0; s < 4; s++){
    float4 p = P4[((size_t)s * 512 + row) * (Hh/4) + t];
    v.x += p.x; v.y += p.y; v.z += p.z; v.w += p.w;
  }
  float4 bb = reinterpret_cast<const float4*>(b1)[t];
  v.x += bb.x; v.y += bb.y; v.z += bb.z; v.w += bb.w;
  float ps = wred(v.x + v.y + v.z + v.w);
  float pq = wred(v.x*v.x + v.y*v.y + v.z*v.z + v.w*v.w);
  if (!(t & 63)) wsum[t >> 6] = make_float2(ps, pq);
  __syncthreads();
  float S = 0, Q = 0;
#pragma unroll
  for (int i = 0; i < 4; i++){ S += wsum[i].x; Q += wsum[i].y; }
  float mean = S * (1.0f/Hh);
  float rstd = rsqrtf(Q * (1.0f/Hh) - mean*mean + 1e-5f);
  float4 gv  = reinterpret_cast<const float4*>(g)[t];
  float4 bev = reinterpret_cast<const float4*>(be)[t];
  ushort4 o;
  o.x = f2b(gelu_exact((v.x - mean)*rstd*gv.x + bev.x));
  o.y = f2b(gelu_exact((v.y - mean)*rstd*gv.y + bev.y));
  o.z = f2b(gelu_exact((v.z - mean)*rstd*gv.z + bev.z));
  o.w = f2b(gelu_exact((v.w - mean)*rstd*gv.w + bev.w));
  reinterpret_cast<ushort4*>(hb)[(size_t)row * 256 + t] = o;
}

// ---------------- LN+gelu 512-wide (sum 4 partials + bias) -> bf16 ----------------
__global__ __launch_bounds__(128) void k_ln2(
    const float* __restrict__ P,
    const float* __restrict__ b1i, const float* __restrict__ b1t,
    const float* __restrict__ gi,  const float* __restrict__ gt,
    const float* __restrict__ bei, const float* __restrict__ bet,
    ushort* __restrict__ hb2)
{
  __shared__ float2 wsum[2];
  const int row = blockIdx.x, t = threadIdx.x;
  const float* b1 = row >= 256 ? b1t : b1i;
  const float* g  = row >= 256 ? gt  : gi;
  const float* be = row >= 256 ? bet : bei;
  const float4* P4 = reinterpret_cast<const float4*>(P);
  float4 v = make_float4(0,0,0,0);
#pragma unroll
  for (int s = 0; s < 4; s++){
    float4 p = P4[((size_t)s * 512 + row) * (K2v/4) + t];
    v.x += p.x; v.y += p.y; v.z += p.z; v.w += p.w;
  }
  float4 bb = reinterpret_cast<const float4*>(b1)[t];
  v.x += bb.x; v.y += bb.y; v.z += bb.z; v.w += bb.w;
  float ps = wred(v.x + v.y + v.z + v.w);
  float pq = wred(v.x*v.x + v.y*v.y + v.z*v.z + v.w*v.w);
  if (!(t & 63)) wsum[t >> 6] = make_float2(ps, pq);
  __syncthreads();
  float S = wsum[0].x + wsum[1].x, Q = wsum[0].y + wsum[1].y;
  float mean = S * (1.0f/K2v);
  float rstd = rsqrtf(Q * (1.0f/K2v) - mean*mean + 1e-5f);
  float4 gv  = reinterpret_cast<const float4*>(g)[t];
  float4 bev = reinterpret_cast<const float4*>(be)[t];
  ushort4 o;
  o.x = f2b(gelu_exact((v.x - mean)*rstd*gv.x + bev.x));
  o.y = f2b(gelu_exact((v.y - mean)*rstd*gv.y + bev.y));
  o.z = f2b(gelu_exact((v.z - mean)*rstd*gv.z + bev.z));
  o.w = f2b(gelu_exact((v.w - mean)*rstd*gv.w + bev.w));
  reinterpret_cast<ushort4*>(hb2)[(size_t)row * 128 + t] = o;
}

// ---------------- reparam + normalize + KL (sum 8 partials + bias) ----------------
__global__ __launch_bounds__(64) void k_reparam(
    const float* __restrict__ P,
    const float* __restrict__ b2i, const float* __restrict__ b2t,
    const float* __restrict__ epsg, float* __restrict__ z,
    ushort* __restrict__ zb, float* __restrict__ kl)
{
  const int row = blockIdx.x, t = threadIdx.x;
  const float* b2 = row >= 256 ? b2t : b2i;
  const float4* P4 = reinterpret_cast<const float4*>(P);
  float4 mu = make_float4(0,0,0,0), lv = make_float4(0,0,0,0);
#pragma unroll
  for (int s = 0; s < 8; s++){
    float4 a = P4[((size_t)s * 512 + row) * (K2v/4) + t];
    float4 c = P4[((size_t)s * 512 + row) * (K2v/4) + 64 + t];
    mu.x += a.x; mu.y += a.y; mu.z += a.z; mu.w += a.w;
    lv.x += c.x; lv.y += c.y; lv.z += c.z; lv.w += c.w;
  }
  float4 bm = reinterpret_cast<const float4*>(b2)[t];
  float4 bl = reinterpret_cast<const float4*>(b2)[64 + t];
  mu.x += bm.x; mu.y += bm.y; mu.z += bm.z; mu.w += bm.w;
  lv.x += bl.x; lv.y += bl.y; lv.z += bl.z; lv.w += bl.w;
  float4 ev = reinterpret_cast<const float4*>(epsg)[(size_t)row * 64 + t];
  float z0 = mu.x + ev.x * expf(0.5f * lv.x);
  float z1 = mu.y + ev.y * expf(0.5f * lv.y);
  float z2 = mu.z + ev.z * expf(0.5f * lv.z);
  float z3 = mu.w + ev.w * expf(0.5f * lv.w);
  float s2 = wred(z0*z0 + z1*z1 + z2*z2 + z3*z3);
  float klp = (1.0f + lv.x - mu.x*mu.x - expf(lv.x))
            + (1.0f + lv.y - mu.y*mu.y - expf(lv.y))
            + (1.0f + lv.z - mu.z*mu.z - expf(lv.z))
            + (1.0f + lv.w - mu.w*mu.w - expf(lv.w));
  float klt = wred(klp);
  float inv = 1.0f / fmaxf(sqrtf(s2), 1e-12f);
  float4 zv = make_float4(z0*inv, z1*inv, z2*inv, z3*inv);
  reinterpret_cast<float4*>(z)[(size_t)row * 64 + t] = zv;
  ushort4 o; o.x=f2b(zv.x); o.y=f2b(zv.y); o.z=f2b(zv.z); o.w=f2b(zv.w);
  reinterpret_cast<ushort4*>(zb)[(size_t)row * 64 + t] = o;
  if (t == 0) atomicAdd(kl + (row >= 256 ? 1 : 0), -0.5f * klt);
}

// ---------------- score partial-sum (8) + bias; ysy ----------------
__global__ __launch_bounds__(64) void k_sum2(
    const float* __restrict__ P,
    const float* __restrict__ b2i, const float* __restrict__ b2t,
    const float* __restrict__ z, float* __restrict__ score, float* __restrict__ ysy)
{
  const int row = blockIdx.x, t = threadIdx.x;
  const float* b2 = row >= 256 ? b2t : b2i;
  const float4* P4 = reinterpret_cast<const float4*>(P);
  float4 v = make_float4(0,0,0,0);
#pragma unroll
  for (int s = 0; s < 8; s++){
    float4 p = P4[((size_t)s * 512 + row) * (Kk/4) + t];
    v.x += p.x; v.y += p.y; v.z += p.z; v.w += p.w;
  }
  float4 bb = reinterpret_cast<const float4*>(b2)[t];
  v.x += bb.x; v.y += bb.y; v.z += bb.z; v.w += bb.w;
  reinterpret_cast<float4*>(score)[(size_t)row * 64 + t] = v;
  float4 zv = reinterpret_cast<const float4*>(z)[(size_t)row * 64 + t];
  float yp = wred(zv.x*v.x + zv.y*v.y + zv.z*v.z + zv.w*v.w);
  if (t == 0) ysy[row] = yp;
}

// ---------------- pairwise dist_sq + histogram ----------------
__global__ __launch_bounds__(256) void k_dist(const float* __restrict__ z,
                                              float* __restrict__ dist, int* __restrict__ ghist){
  __shared__ __align__(16) float xsh[Kk];
  __shared__ int hl[8192];
  const int i = blockIdx.x, j = threadIdx.x;
  xsh[j] = z[(size_t)i * Kk + j];
#pragma unroll
  for (int k = j; k < 8192; k += 256) hl[k] = 0;
  __syncthreads();
  const float4* y4 = reinterpret_cast<const float4*>(z + (size_t)Bb * Kk);
  const float4* x4 = reinterpret_cast<const float4*>(xsh);
  float acc = 0.0f;
#pragma unroll 4
  for (int d = 0; d < Kk; d += 4){
    float4 xv = x4[d >> 2];
    float4 yv = y4[j * (Kk/4) + (d >> 2)];
    float d0 = xv.x - yv.x, d1 = xv.y - yv.y, d2 = xv.z - yv.z, d3 = xv.w - yv.w;
    acc += d0*d0 + d1*d1 + d2*d2 + d3*d3;
  }
  dist[i * 256 + j] = acc;
  int bin = (int)(acc * 2048.0f);
  bin = bin < 0 ? 0 : (bin > 8191 ? 8191 : bin);
  atomicAdd(&hl[bin], 1);
  __syncthreads();
  for (int k = j; k < 8192; k += 256){
    int c = hl[k];
    if (c) atomicAdd(ghist + k, c);
  }
}

// ---------------- score reduction (+ per-block bw, last-block finalize) ----------------
__global__ __launch_bounds__(256) void k_score(
    const float* __restrict__ z, const float* __restrict__ score,
    const float* __restrict__ dist, const float* __restrict__ ysy,
    const int* __restrict__ ghist, float* __restrict__ scal,
    float* __restrict__ out)
{
  __shared__ __align__(16) float xsh[Kk];
  __shared__ __align__(16) float sxsh[Kk];
  __shared__ int wt4[4];
  __shared__ int bres[2];
  __shared__ float red4[4];
  __shared__ float s_bw2;
  const int i = blockIdx.x, j = threadIdx.x;
  xsh[j]  = z[(size_t)i * Kk + j];
  sxsh[j] = score[(size_t)i * Kk + j];

  // bandwidth from histogram (ranks 32768, 32769)
  {
    const int lane = j & 63, w = j >> 6;
    const int base = j * 32;
    int s = 0;
#pragma unroll
    for (int u = 0; u < 32; u++) s += ghist[base + u];
    int sc = s;
#pragma unroll
    for (int m = 1; m < 64; m <<= 1){
      int o = __shfl_up(sc, m, 64);
      if (lane >= m) sc += o;
    }
    if (lane == 63) wt4[w] = sc;
    __syncthreads();
    int off = 0;
    for (int q = 0; q < w; q++) off += wt4[q];
    int cum = sc + off, basex = cum - s;
#pragma unroll
    for (int rr = 0; rr < 2; rr++){
      int rank = 32768 + rr;
      if (basex < rank && cum >= rank){
        int c = basex;
        for (int u = 0; u < 32; u++){
          c += ghist[base + u];
          if (c >= rank){ bres[rr] = base + u; break; }
        }
      }
    }
    __syncthreads();
    if (j == 0){
      float med = 0.5f * ((bres[0] + 0.5f) + (bres[1] + 0.5f)) * (1.0f / 2048.0f);
      float bw = sqrtf(med * 0.5f);
      bw = fminf(fmaxf(bw, 0.1f), 10.0f);
      s_bw2 = bw * bw;
    }
    __syncthreads();
  }
  const float bw2 = s_bw2;
  const float4* sy4 = reinterpret_cast<const float4*>(score + (size_t)Bb * Kk);
  const float4* x4  = reinterpret_cast<const float4*>(xsh);
  const float4* sx4 = reinterpret_cast<const float4*>(sxsh);
  float ssy = 0, xsy = 0;
#pragma unroll 4
  for (int d = 0; d < Kk; d += 4){
    float4 xv  = x4[d >> 2];
    float4 sxv = sx4[d >> 2];
    float4 syv = sy4[j * (Kk/4) + (d >> 2)];
    ssy += sxv.x*syv.x + sxv.y*syv.y + sxv.z*syv.z + sxv.w*syv.w;
    xsy += xv.x*syv.x + xv.y*syv.y + xv.z*syv.z + xv.w*syv.w;
  }
  float d2 = dist[i * 256 + j];
  float kv = expf(-d2 / (2.0f * bw2));
  float t1 = kv * ssy;
  float t2 = (xsy - ysy[Bb + j]) * kv / bw2;
  float t3 = d2 * kv / (bw2 * bw2) - kv * (float)Kk / bw2;
  float s = wred(t1 + t2 + t3);
  if (!(j & 63)) red4[j >> 6] = s;
  __syncthreads();
  if (j == 0){
    atomicAdd(scal + 2, red4[0] + red4[1] + red4[2] + red4[3]);
    __threadfence();
    int old = atomicAdd(reinterpret_cast<int*>(scal + 4), 1);
    if (old == 255){
      float kli = __int_as_float(atomicAdd(reinterpret_cast<int*>(scal + 0), 0));
      float klt = __int_as_float(atomicAdd(reinterpret_cast<int*>(scal + 1), 0));
      float alg = __int_as_float(atomicAdd(reinterpret_cast<int*>(scal + 2), 0));
      out[0] = 0.5f * (kli + klt) * (1.0f/256.0f) + 0.1f * alg * (1.0f/65536.0f);
    }
  }
}

extern "C" void kernel_launch(void* const* d_in, const int* in_sizes, int n_in,
                              void* d_out, int out_size, void* d_ws, size_t ws_size,
                              hipStream_t stream) {
  (void)in_sizes; (void)n_in; (void)out_size; (void)ws_size;
  const float* img  = (const float*)d_in[0];
  const float* txt  = (const float*)d_in[1];
  const float* epsi = (const float*)d_in[2];
  const float* epst = (const float*)d_in[3];
  const int*   mask = (const int*)d_in[4];
  const float* eW1i = (const float*)d_in[5];
  const float* eb1i = (const float*)d_in[6];
  const float* egi  = (const float*)d_in[7];
  const float* ebei = (const float*)d_in[8];
  const float* eW2i = (const float*)d_in[9];
  const float* eb2i = (const float*)d_in[10];
  const float* eW1t = (const float*)d_in[11];
  const float* eb1t = (const float*)d_in[12];
  const float* egt  = (const float*)d_in[13];
  const float* ebet = (const float*)d_in[14];
  const float* eW2t = (const float*)d_in[15];
  const float* eb2t = (const float*)d_in[16];
  const float* sW1i = (const float*)d_in[17];
  const float* sb1i = (const float*)d_in[18];
  const float* sgi  = (const float*)d_in[19];
  const float* sbei = (const float*)d_in[20];
  const float* sW2i = (const float*)d_in[21];
  const float* sb2i = (const float*)d_in[22];
  const float* sW1t = (const float*)d_in[23];
  const float* sb1t = (const float*)d_in[24];
  const float* sgt  = (const float*)d_in[25];
  const float* sbet = (const float*)d_in[26];
  const float* sW2t = (const float*)d_in[27];
  const float* sb2t = (const float*)d_in[28];

  float*  ws    = (float*)d_ws;
  float*  epsg  = ws + OFF_EPSG;
  float*  P     = ws + OFF_P;
  float*  z     = ws + OFF_Z;
  float*  score = ws + OFF_SCORE;
  float*  dist  = ws + OFF_DIST;
  int*    ghist = (int*)(ws + OFF_HIST);
  float*  scal  = ws + OFF_SCAL;
  float*  ysy   = ws + OFF_YSY;
  int*    seql  = (int*)(ws + OFF_SEQL);
  ushort* ub    = (ushort*)(ws + OFF_BF);
  ushort* xgb   = ub + UB_XG;
  ushort* hb    = ub + UB_HACT;
  ushort* zb    = ub + UB_ZB;
  ushort* wt    = ub + UB_WT;

  k_init<<<9, 256, 0, stream>>>(mask, seql, ghist, scal);
  k_gather_conv<<<3328, 256, 0, stream>>>(img, txt, epsi, epst, seql,
                                          eW1i, eW1t, eW2i, eW2t,
                                          sW1i, sW1t, sW2i, sW2t,
                                          xgb, epsg, wt);
  // enc GEMM1: [512,768]@[768,1024], ks=4
  k_mgemm<128,192,1024,768><<<dim3(16,4,4), 256, 0, stream>>>(xgb, wt+WT_EW1I, wt+WT_EW1T, P);
  k_ln1<<<512, 256, 0, stream>>>(P, eb1i, eb1t, egi, egt, ebei, ebet, hb);
  // enc GEMM2: [512,1024]@[1024,512], ks=8
  k_mgemm<128,128,512,1024><<<dim3(8,4,8), 256, 0, stream>>>(hb, wt+WT_EW2I, wt+WT_EW2T, P);
  k_reparam<<<512, 64, 0, stream>>>(P, eb2i, eb2t, epsg, z, zb, scal);
  // sc GEMM1: [512,256]@[256,512], ks=4
  k_mgemm<64,64,512,256><<<dim3(8,8,4), 256, 0, stream>>>(zb, wt+WT_SW1I, wt+WT_SW1T, P);
  k_ln2<<<512, 128, 0, stream>>>(P, sb1i, sb1t, sgi, sgt, sbei, sbet, hb);
  // sc GEMM2: [512,512]@[512,256], ks=8
  k_mgemm<64,64,256,512><<<dim3(4,8,8), 256, 0, stream>>>(hb, wt+WT_SW2I, wt+WT_SW2T, P);
  k_sum2<<<512, 64, 0, stream>>>(P, sb2i, sb2t, z, score, ysy);

  k_dist<<<256, 256, 0, stream>>>(z, dist, ghist);
  k_score<<<256, 256, 0, stream>>>(z, score, dist, ysy, ghist, scal, (float*)d_out);
}